// Round 7
// baseline (109.062 us; speedup 1.0000x reference)
//
#include <hip/hip_runtime.h>

#define TMAX 64
#define BPB  64              // batches per block
#define RPB  14              // rows (c*7+y) per batch
#define NTHR (BPB * RPB)     // 896 threads = 14 waves

__global__ __launch_bounds__(NTHR) void snn_fused(
    const float* __restrict__ x,       // [B,1,10,10]
    const float* __restrict__ conv_w,  // [2,1,4,4]
    const float* __restrict__ conv_b,  // [2]
    const float* __restrict__ fc_w,    // [10,72]
    const float* __restrict__ fc_b,    // [10]
    const int*   __restrict__ nsteps,  // scalar
    float*       __restrict__ out,     // [B,10]
    int B)
{
    __shared__ double d_F[TMAX];       // F(m) = 0.9^m - 0.8^m  (double)
    __shared__ float  s_r[TMAX];       // r_s = G(T-1-s)  (time-indexed)
    __shared__ float  s_rb[TMAX];      // bit-position -> r  (addc bit order)
    __shared__ float  s_tab[8][256];   // byte tables over s_rb
    __shared__ float  s_fcw[720];
    __shared__ float  s_fcb[16];
    __shared__ float  s_cb;            // C_b = sum_{m<T} F(m)
    // mask-exchange region, reused as reduction staging after a barrier
    __shared__ union {
        uint2 masks[BPB * RPB * 7];    // 6272 * 8B = 50176 B
        float red[BPB * 12 * 10];      // 7680 * 4B = 30720 B
    } u;

    const int tid = threadIdx.x;
    int T = nsteps[0];
    if (T > TMAX) T = TMAX;
    if (T < 0) T = 0;
    const int tlo = T < 32 ? T : 32;
    const int thi = T > 32 ? (T - 32) : 0;

    // --- setup: F(m) in double ---
    if (tid < TMAX) {
        double p9 = 1.0, p8 = 1.0;
        for (int k = 0; k < tid; ++k) { p9 *= 0.9; p8 *= 0.8; }
        d_F[tid] = p9 - p8;
    }
    for (int idx = tid; idx < 720; idx += NTHR) s_fcw[idx] = fc_w[idx];
    if (tid < 10) s_fcb[tid] = fc_b[tid];
    __syncthreads();

    // --- r_s = G(T-1-s), double accumulate ---
    if (tid < TMAX) {
        double r = 0.0;
        if (tid < T) {
            const int n = T - 1 - tid;
            for (int uu = 0; uu <= n; ++uu) r += d_F[n - uu] * d_F[uu];
        }
        s_r[tid] = (float)r;
    }
    if (tid == 0) {
        double cb = 0.0;
        for (int m = 0; m < T; ++m) cb += d_F[m];
        s_cb = (float)cb;
    }
    __syncthreads();

    // --- bit-position -> r map (m = 2m + sp ordering) ---
    if (tid < 32) {
        s_rb[tid] = (tid < tlo) ? s_r[tlo - 1 - tid] : 0.f;
    } else if (tid < 64) {
        const int p = tid - 32;
        s_rb[tid] = (p < thi) ? s_r[tlo + thi - 1 - p] : 0.f;
    }
    __syncthreads();

    // --- byte lookup tables ---
    if (tid < 256) {
        const int v8 = tid; // 0..255
        #pragma unroll
        for (int k = 0; k < 8; ++k) {
            float ssum = 0.f;
            #pragma unroll
            for (int bb = 0; bb < 8; ++bb)
                if ((v8 >> bb) & 1) ssum += s_rb[k * 8 + bb];
            s_tab[k][v8] = ssum;
        }
    }
    __syncthreads();

    const float cbsum = s_cb;

    // dense lane mapping: tid -> (batch-local bl, row r = c*7 + y)
    const int bl = tid / RPB;          // 0..63
    const int r  = tid - bl * RPB;     // 0..13
    const int c  = r / 7;
    const int y  = r - c * 7;          // 0..6
    const int b  = blockIdx.x * BPB + bl;
    const int bc = (b < B) ? b : (B - 1);   // clamp: convergent, OOB-safe loads

    const float* xb = x + bc * 100;
    const float cbias = conv_b[c];

    // ---- conv for row y: exact (ky asc, kx asc) sequential order, then +bias ----
    float gg7[7];
    #pragma unroll
    for (int xx = 0; xx < 7; ++xx) gg7[xx] = 0.f;
    {
        float wc[16];
        const float4* wq = reinterpret_cast<const float4*>(conv_w + c * 16);
        #pragma unroll
        for (int k = 0; k < 4; ++k) {
            float4 t = wq[k];
            wc[4*k+0] = t.x; wc[4*k+1] = t.y; wc[4*k+2] = t.z; wc[4*k+3] = t.w;
        }
        #pragma unroll
        for (int ky = 0; ky < 4; ++ky) {
            float xrow[10];
            const float2* q = reinterpret_cast<const float2*>(xb + (y + ky) * 10);
            #pragma unroll
            for (int k = 0; k < 5; ++k) { float2 t = q[k]; xrow[2*k] = t.x; xrow[2*k+1] = t.y; }
            #pragma unroll
            for (int xx = 0; xx < 7; ++xx) {
                float a = gg7[xx];
                #pragma unroll
                for (int kx = 0; kx < 4; ++kx)
                    a = __fadd_rn(a, __fmul_rn(wc[ky*4 + kx], xrow[xx + kx]));
                gg7[xx] = a;
            }
        }
    }
    #pragma unroll
    for (int xx = 0; xx < 7; ++xx) gg7[xx] = __fadd_rn(gg7[xx], cbias);

    // ---- LIF sim: exact reference fp32 arithmetic; spike bits via m = 2m + sp ----
    float v[7], ii[7];
    unsigned int mlo[7], mhi[7];
    float fzero = 0.0f;
    #pragma unroll
    for (int xx = 0; xx < 7; ++xx) { v[xx] = 0.f; ii[xx] = 0.f; mlo[xx] = 0u; mhi[xx] = 0u; }

    #pragma unroll 4
    for (int t = 0; t < tlo; ++t) {
        #pragma unroll
        for (int xx = 0; xx < 7; ++xx) {
            const float imv  = __fsub_rn(ii[xx], v[xx]);
            const float vdec = __fadd_rn(v[xx], __fmul_rn(0.1f, imv));
            const float idec = __fsub_rn(ii[xx], __fmul_rn(0.2f, ii[xx]));
            float vnew;
            asm("v_cmp_lt_f32 vcc, 1.0, %[vd]\n\t"
                "v_cndmask_b32 %[vn], %[vd], %[vz], vcc\n\t"
                "v_addc_co_u32 %[mm], vcc, %[mm], %[mm], vcc"
                : [vn]"=v"(vnew), [mm]"+v"(mlo[xx])
                : [vd]"v"(vdec), [vz]"v"(fzero)
                : "vcc");
            v[xx]  = vnew;
            ii[xx] = __fadd_rn(idec, gg7[xx]);
        }
    }
    #pragma unroll 4
    for (int t = 0; t < thi; ++t) {
        #pragma unroll
        for (int xx = 0; xx < 7; ++xx) {
            const float imv  = __fsub_rn(ii[xx], v[xx]);
            const float vdec = __fadd_rn(v[xx], __fmul_rn(0.1f, imv));
            const float idec = __fsub_rn(ii[xx], __fmul_rn(0.2f, ii[xx]));
            float vnew;
            asm("v_cmp_lt_f32 vcc, 1.0, %[vd]\n\t"
                "v_cndmask_b32 %[vn], %[vd], %[vz], vcc\n\t"
                "v_addc_co_u32 %[mm], vcc, %[mm], %[mm], vcc"
                : [vn]"=v"(vnew), [mm]"+v"(mhi[xx])
                : [vd]"v"(vdec), [vz]"v"(fzero)
                : "vcc");
            v[xx]  = vnew;
            ii[xx] = __fadd_rn(idec, gg7[xx]);
        }
    }

    // ---- exchange masks through LDS ----
    {
        uint2* mrow = &u.masks[(bl * RPB + r) * 7];
        #pragma unroll
        for (int xx = 0; xx < 7; ++xx) mrow[xx] = make_uint2(mlo[xx], mhi[xx]);
    }
    __syncthreads();

    // ---- pooled row y (y<6): OR of 4 masks (own row + row y+1 from LDS) + LUT + FC ----
    float outacc[10];
    #pragma unroll
    for (int o = 0; o < 10; ++o) outacc[o] = 0.f;

    if (y < 6) {
        const uint2* nrow = &u.masks[(bl * RPB + c * 7 + y + 1) * 7];
        uint2 nb[7];
        #pragma unroll
        for (int xx = 0; xx < 7; ++xx) nb[xx] = nrow[xx];

        const int jbase = c * 36 + y * 6;
        #pragma unroll
        for (int px = 0; px < 6; ++px) {
            const unsigned int pl = mlo[px] | mlo[px+1] | nb[px].x | nb[px+1].x;
            const unsigned int ph = mhi[px] | mhi[px+1] | nb[px].y | nb[px+1].y;
            float a = s_tab[0][pl & 255] + s_tab[1][(pl >> 8) & 255]
                    + s_tab[2][(pl >> 16) & 255] + s_tab[3][pl >> 24]
                    + s_tab[4][ph & 255] + s_tab[5][(ph >> 8) & 255]
                    + s_tab[6][(ph >> 16) & 255] + s_tab[7][ph >> 24];
            const int j = jbase + px;
            #pragma unroll
            for (int o = 0; o < 10; ++o)
                outacc[o] = fmaf(s_fcw[o * 72 + j], a, outacc[o]);
        }
    }
    __syncthreads();   // all mask reads done; safe to reuse region as float red[]

    if (y < 6) {
        float* dst = &u.red[(bl * 12 + c * 6 + y) * 10];
        #pragma unroll
        for (int o = 0; o < 10; ++o) dst[o] = outacc[o];
    }
    __syncthreads();

    // ---- fixed-order 12-way reduction + bias response + store ----
    if (tid < BPB * 10) {
        const int bl2 = tid / 10;
        const int o   = tid - bl2 * 10;
        const int b2  = blockIdx.x * BPB + bl2;
        if (b2 < B) {
            float s = 0.f;
            #pragma unroll
            for (int pr = 0; pr < 12; ++pr)
                s += u.red[(bl2 * 12 + pr) * 10 + o];
            out[b2 * 10 + o] = fmaf(cbsum, s_fcb[o], s);
        }
    }
}

extern "C" void kernel_launch(void* const* d_in, const int* in_sizes, int n_in,
                              void* d_out, int out_size, void* d_ws, size_t ws_size,
                              hipStream_t stream) {
    const float* x      = (const float*)d_in[0];
    const float* conv_w = (const float*)d_in[1];
    const float* conv_b = (const float*)d_in[2];
    const float* fc_w   = (const float*)d_in[3];
    const float* fc_b   = (const float*)d_in[4];
    const int*   nsteps = (const int*)d_in[5];
    float* outp = (float*)d_out;

    const int B = in_sizes[0] / 100;
    const int grid = (B + BPB - 1) / BPB;
    snn_fused<<<grid, NTHR, 0, stream>>>(x, conv_w, conv_b, fc_w, fc_b, nsteps, outp, B);
}

// Round 8
// 94.014 us; speedup vs baseline: 1.1601x; 1.1601x over previous
//
#include <hip/hip_runtime.h>

#define TMAX 64
#define BPB  32              // batches per block
#define RPB  14              // rows (c*7+y) per batch
#define NTHR (BPB * RPB)     // 448 threads = 7 waves

__global__ __launch_bounds__(NTHR) void snn_fused(
    const float* __restrict__ x,       // [B,1,10,10]
    const float* __restrict__ conv_w,  // [2,1,4,4]
    const float* __restrict__ conv_b,  // [2]
    const float* __restrict__ fc_w,    // [10,72]
    const float* __restrict__ fc_b,    // [10]
    const int*   __restrict__ nsteps,  // scalar
    float*       __restrict__ out,     // [B,10]
    int B)
{
    __shared__ double d_F[TMAX];       // F(m) = 0.9^m - 0.8^m  (double)
    __shared__ float  s_r[TMAX];       // r_s = G(T-1-s)  (time-indexed)
    __shared__ float  s_rb[TMAX];      // bit-position -> r  (addc bit order)
    __shared__ float  s_tab[8][256];   // byte tables over s_rb
    __shared__ float  s_fcw[720];
    __shared__ float  s_fcb[16];
    __shared__ float  s_cb;            // C_b = sum_{m<T} F(m)
    // mask-exchange region, reused as reduction staging after a barrier
    __shared__ union {
        uint2 masks[BPB * RPB * 7];    // 3136 * 8B = 25088 B
        float red[BPB * 12 * 10];      // 3840 * 4B = 15360 B
    } u;

    const int tid = threadIdx.x;
    int T = nsteps[0];
    if (T > TMAX) T = TMAX;
    if (T < 0) T = 0;
    const int tlo = T < 32 ? T : 32;
    const int thi = T > 32 ? (T - 32) : 0;

    // --- setup: F(m) in double ---
    if (tid < TMAX) {
        double p9 = 1.0, p8 = 1.0;
        for (int k = 0; k < tid; ++k) { p9 *= 0.9; p8 *= 0.8; }
        d_F[tid] = p9 - p8;
    }
    for (int idx = tid; idx < 720; idx += NTHR) s_fcw[idx] = fc_w[idx];
    if (tid < 10) s_fcb[tid] = fc_b[tid];
    __syncthreads();

    // --- r_s = G(T-1-s), double accumulate ---
    if (tid < TMAX) {
        double r = 0.0;
        if (tid < T) {
            const int n = T - 1 - tid;
            for (int uu = 0; uu <= n; ++uu) r += d_F[n - uu] * d_F[uu];
        }
        s_r[tid] = (float)r;
    }
    if (tid == 0) {
        double cb = 0.0;
        for (int m = 0; m < T; ++m) cb += d_F[m];
        s_cb = (float)cb;
    }
    __syncthreads();

    // --- bit-position -> r map (m = 2m + sp ordering) ---
    if (tid < 32) {
        s_rb[tid] = (tid < tlo) ? s_r[tlo - 1 - tid] : 0.f;
    } else if (tid < 64) {
        const int p = tid - 32;
        s_rb[tid] = (p < thi) ? s_r[tlo + thi - 1 - p] : 0.f;
    }
    __syncthreads();

    // --- byte lookup tables ---
    if (tid < 256) {
        const int v8 = tid; // 0..255
        #pragma unroll
        for (int k = 0; k < 8; ++k) {
            float ssum = 0.f;
            #pragma unroll
            for (int bb = 0; bb < 8; ++bb)
                if ((v8 >> bb) & 1) ssum += s_rb[k * 8 + bb];
            s_tab[k][v8] = ssum;
        }
    }
    __syncthreads();

    const float cbsum = s_cb;

    // dense lane mapping: tid -> (batch-local bl, row r = c*7 + y)
    const int bl = tid / RPB;          // 0..31
    const int r  = tid - bl * RPB;     // 0..13
    const int c  = r / 7;
    const int y  = r - c * 7;          // 0..6
    const int b  = blockIdx.x * BPB + bl;
    const int bc = (b < B) ? b : (B - 1);   // clamp: convergent, OOB-safe loads

    const float* xb = x + bc * 100;
    const float cbias = conv_b[c];

    // ---- conv for row y: exact (ky asc, kx asc) sequential order, then +bias ----
    float gg7[7];
    #pragma unroll
    for (int xx = 0; xx < 7; ++xx) gg7[xx] = 0.f;
    {
        float wc[16];
        const float4* wq = reinterpret_cast<const float4*>(conv_w + c * 16);
        #pragma unroll
        for (int k = 0; k < 4; ++k) {
            float4 t = wq[k];
            wc[4*k+0] = t.x; wc[4*k+1] = t.y; wc[4*k+2] = t.z; wc[4*k+3] = t.w;
        }
        #pragma unroll
        for (int ky = 0; ky < 4; ++ky) {
            float xrow[10];
            const float2* q = reinterpret_cast<const float2*>(xb + (y + ky) * 10);
            #pragma unroll
            for (int k = 0; k < 5; ++k) { float2 t = q[k]; xrow[2*k] = t.x; xrow[2*k+1] = t.y; }
            #pragma unroll
            for (int xx = 0; xx < 7; ++xx) {
                float a = gg7[xx];
                #pragma unroll
                for (int kx = 0; kx < 4; ++kx)
                    a = __fadd_rn(a, __fmul_rn(wc[ky*4 + kx], xrow[xx + kx]));
                gg7[xx] = a;
            }
        }
    }
    #pragma unroll
    for (int xx = 0; xx < 7; ++xx) gg7[xx] = __fadd_rn(gg7[xx], cbias);

    // ---- LIF sim: exact reference fp32 arithmetic; spike bits via m = 2m + sp ----
    float v[7], ii[7];
    unsigned int mlo[7], mhi[7];
    float fzero = 0.0f;
    #pragma unroll
    for (int xx = 0; xx < 7; ++xx) { v[xx] = 0.f; ii[xx] = 0.f; mlo[xx] = 0u; mhi[xx] = 0u; }

    #pragma unroll 4
    for (int t = 0; t < tlo; ++t) {
        #pragma unroll
        for (int xx = 0; xx < 7; ++xx) {
            const float imv  = __fsub_rn(ii[xx], v[xx]);
            const float vdec = __fadd_rn(v[xx], __fmul_rn(0.1f, imv));
            const float idec = __fsub_rn(ii[xx], __fmul_rn(0.2f, ii[xx]));
            float vnew;
            asm("v_cmp_lt_f32 vcc, 1.0, %[vd]\n\t"
                "v_cndmask_b32 %[vn], %[vd], %[vz], vcc\n\t"
                "v_addc_co_u32 %[mm], vcc, %[mm], %[mm], vcc"
                : [vn]"=v"(vnew), [mm]"+v"(mlo[xx])
                : [vd]"v"(vdec), [vz]"v"(fzero)
                : "vcc");
            v[xx]  = vnew;
            ii[xx] = __fadd_rn(idec, gg7[xx]);
        }
    }
    #pragma unroll 4
    for (int t = 0; t < thi; ++t) {
        #pragma unroll
        for (int xx = 0; xx < 7; ++xx) {
            const float imv  = __fsub_rn(ii[xx], v[xx]);
            const float vdec = __fadd_rn(v[xx], __fmul_rn(0.1f, imv));
            const float idec = __fsub_rn(ii[xx], __fmul_rn(0.2f, ii[xx]));
            float vnew;
            asm("v_cmp_lt_f32 vcc, 1.0, %[vd]\n\t"
                "v_cndmask_b32 %[vn], %[vd], %[vz], vcc\n\t"
                "v_addc_co_u32 %[mm], vcc, %[mm], %[mm], vcc"
                : [vn]"=v"(vnew), [mm]"+v"(mhi[xx])
                : [vd]"v"(vdec), [vz]"v"(fzero)
                : "vcc");
            v[xx]  = vnew;
            ii[xx] = __fadd_rn(idec, gg7[xx]);
        }
    }

    // ---- exchange masks through LDS ----
    {
        uint2* mrow = &u.masks[tid * 7];
        #pragma unroll
        for (int xx = 0; xx < 7; ++xx) mrow[xx] = make_uint2(mlo[xx], mhi[xx]);
    }
    __syncthreads();

    // ---- pooled row y (y<6): OR of 4 masks (own row + row y+1 from LDS) + LUT + FC ----
    float outacc[10];
    #pragma unroll
    for (int o = 0; o < 10; ++o) outacc[o] = 0.f;

    if (y < 6) {
        const uint2* nrow = &u.masks[(tid + 1) * 7];   // row r+1 = (bl, c, y+1)
        uint2 nb[7];
        #pragma unroll
        for (int xx = 0; xx < 7; ++xx) nb[xx] = nrow[xx];

        const int jbase = c * 36 + y * 6;
        #pragma unroll
        for (int px = 0; px < 6; ++px) {
            const unsigned int pl = mlo[px] | mlo[px+1] | nb[px].x | nb[px+1].x;
            const unsigned int ph = mhi[px] | mhi[px+1] | nb[px].y | nb[px+1].y;
            float a = s_tab[0][pl & 255] + s_tab[1][(pl >> 8) & 255]
                    + s_tab[2][(pl >> 16) & 255] + s_tab[3][pl >> 24]
                    + s_tab[4][ph & 255] + s_tab[5][(ph >> 8) & 255]
                    + s_tab[6][(ph >> 16) & 255] + s_tab[7][ph >> 24];
            const int j = jbase + px;
            #pragma unroll
            for (int o = 0; o < 10; ++o)
                outacc[o] = fmaf(s_fcw[o * 72 + j], a, outacc[o]);
        }
    }
    __syncthreads();   // all mask reads done; safe to reuse region as float red[]

    if (y < 6) {
        float* dst = &u.red[(bl * 12 + c * 6 + y) * 10];
        #pragma unroll
        for (int o = 0; o < 10; ++o) dst[o] = outacc[o];
    }
    __syncthreads();

    // ---- fixed-order 12-way reduction + bias response + store ----
    if (tid < BPB * 10) {
        const int bl2 = tid / 10;
        const int o   = tid - bl2 * 10;
        const int b2  = blockIdx.x * BPB + bl2;
        if (b2 < B) {
            float s = 0.f;
            #pragma unroll
            for (int pr = 0; pr < 12; ++pr)
                s += u.red[(bl2 * 12 + pr) * 10 + o];
            out[b2 * 10 + o] = fmaf(cbsum, s_fcb[o], s);
        }
    }
}

extern "C" void kernel_launch(void* const* d_in, const int* in_sizes, int n_in,
                              void* d_out, int out_size, void* d_ws, size_t ws_size,
                              hipStream_t stream) {
    const float* x      = (const float*)d_in[0];
    const float* conv_w = (const float*)d_in[1];
    const float* conv_b = (const float*)d_in[2];
    const float* fc_w   = (const float*)d_in[3];
    const float* fc_b   = (const float*)d_in[4];
    const int*   nsteps = (const int*)d_in[5];
    float* outp = (float*)d_out;

    const int B = in_sizes[0] / 100;
    const int grid = (B + BPB - 1) / BPB;
    snn_fused<<<grid, NTHR, 0, stream>>>(x, conv_w, conv_b, fc_w, fc_b, nsteps, outp, B);
}

// Round 9
// 83.086 us; speedup vs baseline: 1.3126x; 1.1315x over previous
//
#include <hip/hip_runtime.h>

#define TMAX 64

__global__ __launch_bounds__(256) void snn_fused(
    const float* __restrict__ x,       // [B,1,10,10]
    const float* __restrict__ conv_w,  // [2,1,4,4]
    const float* __restrict__ conv_b,  // [2]
    const float* __restrict__ fc_w,    // [10,72]
    const float* __restrict__ fc_b,    // [10]
    const int*   __restrict__ nsteps,  // scalar
    float*       __restrict__ out,     // [B,10]
    int B)
{
    __shared__ double d_F[TMAX];       // F(m) = 0.9^m - 0.8^m  (double)
    __shared__ float  s_r[TMAX];       // r_s = G(T-1-s)  (time-indexed)
    __shared__ float  s_rb[TMAX];      // bit-position -> r  (addc bit order)
    __shared__ float  s_tab[8][256];   // byte tables over s_rb
    __shared__ float  s_fcw[720];
    __shared__ float  s_fcb[16];
    __shared__ float  s_cb;            // C_b = sum_{m<T} F(m)

    const int tid = threadIdx.x;
    int T = nsteps[0];
    if (T > TMAX) T = TMAX;
    if (T < 0) T = 0;
    const int tlo = T < 32 ? T : 32;
    const int thi = T > 32 ? (T - 32) : 0;

    // --- setup: F(m) in double ---
    if (tid < TMAX) {
        double p9 = 1.0, p8 = 1.0;
        for (int k = 0; k < tid; ++k) { p9 *= 0.9; p8 *= 0.8; }
        d_F[tid] = p9 - p8;
    }
    for (int idx = tid; idx < 720; idx += 256) s_fcw[idx] = fc_w[idx];
    if (tid < 10) s_fcb[tid] = fc_b[tid];
    __syncthreads();

    // --- r_s = G(T-1-s), double accumulate ---
    if (tid < TMAX) {
        double r = 0.0;
        if (tid < T) {
            const int n = T - 1 - tid;
            for (int u = 0; u <= n; ++u) r += d_F[n - u] * d_F[u];
        }
        s_r[tid] = (float)r;
    }
    if (tid == 0) {
        double cb = 0.0;
        for (int m = 0; m < T; ++m) cb += d_F[m];
        s_cb = (float)cb;
    }
    __syncthreads();

    // --- bit-position -> r map (m = 2m + sp ordering) ---
    if (tid < 32) {
        s_rb[tid] = (tid < tlo) ? s_r[tlo - 1 - tid] : 0.f;
    } else if (tid < 64) {
        const int p = tid - 32;
        s_rb[tid] = (p < thi) ? s_r[tlo + thi - 1 - p] : 0.f;
    }
    __syncthreads();

    // --- byte lookup tables ---
    {
        const int v8 = tid; // 0..255
        #pragma unroll
        for (int k = 0; k < 8; ++k) {
            float ssum = 0.f;
            #pragma unroll
            for (int bb = 0; bb < 8; ++bb)
                if ((v8 >> bb) & 1) ssum += s_rb[k * 8 + bb];
            s_tab[k][v8] = ssum;
        }
    }
    __syncthreads();

    const float cbsum = s_cb;

    // lane mapping: 16 lanes per batch: sub = c*8 + y; y==7 lanes pad (clamp to row 6)
    const int gt  = blockIdx.x * 256 + tid;
    const int sub = gt & 15;
    const int b   = gt >> 4;
    const int c   = sub >> 3;
    const int y   = sub & 7;
    const int ysim = (y < 6) ? y : 6;
    if (b >= B) return;

    const float* xb = x + b * 100;
    const float cbias = conv_b[c];

    // ---- conv for row ysim: fma-contracted (ky asc, kx asc) order, then +bias ----
    float gg7[7];
    #pragma unroll
    for (int xx = 0; xx < 7; ++xx) gg7[xx] = 0.f;
    {
        float wc[16];
        const float4* wq = reinterpret_cast<const float4*>(conv_w + c * 16);
        #pragma unroll
        for (int k = 0; k < 4; ++k) {
            float4 t = wq[k];
            wc[4*k+0] = t.x; wc[4*k+1] = t.y; wc[4*k+2] = t.z; wc[4*k+3] = t.w;
        }
        #pragma unroll
        for (int ky = 0; ky < 4; ++ky) {
            float xrow[10];
            const float2* q = reinterpret_cast<const float2*>(xb + (ysim + ky) * 10);
            #pragma unroll
            for (int k = 0; k < 5; ++k) { float2 t = q[k]; xrow[2*k] = t.x; xrow[2*k+1] = t.y; }
            #pragma unroll
            for (int xx = 0; xx < 7; ++xx) {
                float a = gg7[xx];
                #pragma unroll
                for (int kx = 0; kx < 4; ++kx)
                    a = fmaf(wc[ky*4 + kx], xrow[xx + kx], a);
                gg7[xx] = a;
            }
        }
    }
    #pragma unroll
    for (int xx = 0; xx < 7; ++xx) gg7[xx] = __fadd_rn(gg7[xx], cbias);

    // ---- LIF sim: fma-contracted recurrence (<=1ulp from reference per step);
    //      spike bits via m = 2m + sp ----
    float v[7], ii[7];
    unsigned int mlo[7], mhi[7];
    float fzero = 0.0f;
    #pragma unroll
    for (int xx = 0; xx < 7; ++xx) { v[xx] = 0.f; ii[xx] = 0.f; mlo[xx] = 0u; mhi[xx] = 0u; }

    #pragma unroll 4
    for (int t = 0; t < tlo; ++t) {
        #pragma unroll
        for (int xx = 0; xx < 7; ++xx) {
            const float imv  = __fsub_rn(ii[xx], v[xx]);
            const float vdec = fmaf(0.1f, imv, v[xx]);          // v + 0.1*(i-v), fused
            const float idec = fmaf(-0.2f, ii[xx], ii[xx]);     // i - 0.2*i, fused
            float vnew;
            asm("v_cmp_lt_f32 vcc, 1.0, %[vd]\n\t"
                "v_cndmask_b32 %[vn], %[vd], %[vz], vcc\n\t"
                "v_addc_co_u32 %[mm], vcc, %[mm], %[mm], vcc"
                : [vn]"=v"(vnew), [mm]"+v"(mlo[xx])
                : [vd]"v"(vdec), [vz]"v"(fzero)
                : "vcc");
            v[xx]  = vnew;
            ii[xx] = __fadd_rn(idec, gg7[xx]);
        }
    }
    #pragma unroll 4
    for (int t = 0; t < thi; ++t) {
        #pragma unroll
        for (int xx = 0; xx < 7; ++xx) {
            const float imv  = __fsub_rn(ii[xx], v[xx]);
            const float vdec = fmaf(0.1f, imv, v[xx]);
            const float idec = fmaf(-0.2f, ii[xx], ii[xx]);
            float vnew;
            asm("v_cmp_lt_f32 vcc, 1.0, %[vd]\n\t"
                "v_cndmask_b32 %[vn], %[vd], %[vz], vcc\n\t"
                "v_addc_co_u32 %[mm], vcc, %[mm], %[mm], vcc"
                : [vn]"=v"(vnew), [mm]"+v"(mhi[xx])
                : [vd]"v"(vdec), [vz]"v"(fzero)
                : "vcc");
            v[xx]  = vnew;
            ii[xx] = __fadd_rn(idec, gg7[xx]);
        }
    }

    // ---- neighbor-row masks via shfl (lane y+1, same c) ----
    unsigned int nlo[7], nhi[7];
    #pragma unroll
    for (int xx = 0; xx < 7; ++xx) {
        nlo[xx] = __shfl_down(mlo[xx], 1);
        nhi[xx] = __shfl_down(mhi[xx], 1);
    }

    // ---- pooled row y (if y<6): OR of 4 masks + LUT + FC partials ----
    float outacc[10];
    #pragma unroll
    for (int o = 0; o < 10; ++o) outacc[o] = 0.f;

    if (y < 6) {
        const int jbase = c * 36 + y * 6;
        #pragma unroll
        for (int px = 0; px < 6; ++px) {
            const unsigned int pl = mlo[px] | mlo[px+1] | nlo[px] | nlo[px+1];
            const unsigned int ph = mhi[px] | mhi[px+1] | nhi[px] | nhi[px+1];
            float a = s_tab[0][pl & 255] + s_tab[1][(pl >> 8) & 255]
                    + s_tab[2][(pl >> 16) & 255] + s_tab[3][pl >> 24]
                    + s_tab[4][ph & 255] + s_tab[5][(ph >> 8) & 255]
                    + s_tab[6][(ph >> 16) & 255] + s_tab[7][ph >> 24];
            const int j = jbase + px;
            #pragma unroll
            for (int o = 0; o < 10; ++o)
                outacc[o] = fmaf(s_fcw[o * 72 + j], a, outacc[o]);
        }
    }

    // ---- reduce over the 16-lane group, add bias response, store ----
    #pragma unroll
    for (int o = 0; o < 10; ++o) {
        float t = outacc[o];
        t += __shfl_xor(t, 1);
        t += __shfl_xor(t, 2);
        t += __shfl_xor(t, 4);
        t += __shfl_xor(t, 8);
        if (sub == 0) out[b * 10 + o] = fmaf(cbsum, s_fcb[o], t);
    }
}

extern "C" void kernel_launch(void* const* d_in, const int* in_sizes, int n_in,
                              void* d_out, int out_size, void* d_ws, size_t ws_size,
                              hipStream_t stream) {
    const float* x      = (const float*)d_in[0];
    const float* conv_w = (const float*)d_in[1];
    const float* conv_b = (const float*)d_in[2];
    const float* fc_w   = (const float*)d_in[3];
    const float* fc_b   = (const float*)d_in[4];
    const int*   nsteps = (const int*)d_in[5];
    float* outp = (float*)d_out;

    const int B = in_sizes[0] / 100;
    const int total = 16 * B;   // lane = c*8 + y per batch
    const int block = 256;
    const int grid = (total + block - 1) / block;
    snn_fused<<<grid, block, 0, stream>>>(x, conv_w, conv_b, fc_w, fc_b, nsteps, outp, B);
}

// Round 11
// 79.602 us; speedup vs baseline: 1.3701x; 1.0438x over previous
//
#include <hip/hip_runtime.h>

#define TMAX 64

__global__ __launch_bounds__(256) void snn_fused(
    const float* __restrict__ x,       // [B,1,10,10]
    const float* __restrict__ conv_w,  // [2,1,4,4]
    const float* __restrict__ conv_b,  // [2]
    const float* __restrict__ fc_w,    // [10,72]
    const float* __restrict__ fc_b,    // [10]
    const int*   __restrict__ nsteps,  // scalar
    float*       __restrict__ out,     // [B,10]
    int B)
{
    __shared__ double d_F[TMAX];       // F(m) = 0.9^m - 0.8^m  (double)
    __shared__ float  s_r[TMAX];       // r_s = G(T-1-s)  (time-indexed)
    __shared__ float  s_rb[TMAX];      // bit-position -> r  (addc bit order)
    __shared__ float  s_tab[8][256];   // byte tables over s_rb
    __shared__ float  s_fcw[720];
    __shared__ float  s_fcb[16];
    __shared__ float  s_cb;            // C_b = sum_{m<T} F(m)

    const int tid = threadIdx.x;
    int T = nsteps[0];
    if (T > TMAX) T = TMAX;
    if (T < 0) T = 0;
    const int tlo = T < 32 ? T : 32;
    const int thi = T > 32 ? (T - 32) : 0;

    // --- setup: F(m) in double ---
    if (tid < TMAX) {
        double p9 = 1.0, p8 = 1.0;
        for (int k = 0; k < tid; ++k) { p9 *= 0.9; p8 *= 0.8; }
        d_F[tid] = p9 - p8;
    }
    for (int idx = tid; idx < 720; idx += 256) s_fcw[idx] = fc_w[idx];
    if (tid < 10) s_fcb[tid] = fc_b[tid];
    __syncthreads();

    // --- r_s = G(T-1-s), double accumulate ---
    if (tid < TMAX) {
        double r = 0.0;
        if (tid < T) {
            const int n = T - 1 - tid;
            for (int u = 0; u <= n; ++u) r += d_F[n - u] * d_F[u];
        }
        s_r[tid] = (float)r;
    }
    if (tid == 0) {
        double cb = 0.0;
        for (int m = 0; m < T; ++m) cb += d_F[m];
        s_cb = (float)cb;
    }
    __syncthreads();

    // --- bit-position -> r map (m = 2m + sp ordering) ---
    if (tid < 32) {
        s_rb[tid] = (tid < tlo) ? s_r[tlo - 1 - tid] : 0.f;
    } else if (tid < 64) {
        const int p = tid - 32;
        s_rb[tid] = (p < thi) ? s_r[tlo + thi - 1 - p] : 0.f;
    }
    __syncthreads();

    // --- byte lookup tables ---
    {
        const int v8 = tid; // 0..255
        #pragma unroll
        for (int k = 0; k < 8; ++k) {
            float ssum = 0.f;
            #pragma unroll
            for (int bb = 0; bb < 8; ++bb)
                if ((v8 >> bb) & 1) ssum += s_rb[k * 8 + bb];
            s_tab[k][v8] = ssum;
        }
    }
    __syncthreads();

    const float cbsum = s_cb;

    // lane mapping: 16 lanes per batch: sub = c*8 + y; y==7 lanes pad (clamp to row 6)
    const int gt  = blockIdx.x * 256 + tid;
    const int sub = gt & 15;
    const int b   = gt >> 4;
    const int c   = sub >> 3;
    const int y   = sub & 7;
    const int ysim = (y < 6) ? y : 6;
    if (b >= B) return;

    const float* xb = x + b * 100;
    const float cbias = conv_b[c];

    // ---- conv for row ysim: fma-contracted (ky asc, kx asc) order, then +bias ----
    float gg7[7];
    #pragma unroll
    for (int xx = 0; xx < 7; ++xx) gg7[xx] = 0.f;
    {
        float wc[16];
        const float4* wq = reinterpret_cast<const float4*>(conv_w + c * 16);
        #pragma unroll
        for (int k = 0; k < 4; ++k) {
            float4 t = wq[k];
            wc[4*k+0] = t.x; wc[4*k+1] = t.y; wc[4*k+2] = t.z; wc[4*k+3] = t.w;
        }
        #pragma unroll
        for (int ky = 0; ky < 4; ++ky) {
            float xrow[10];
            const float2* q = reinterpret_cast<const float2*>(xb + (ysim + ky) * 10);
            #pragma unroll
            for (int k = 0; k < 5; ++k) { float2 t = q[k]; xrow[2*k] = t.x; xrow[2*k+1] = t.y; }
            #pragma unroll
            for (int xx = 0; xx < 7; ++xx) {
                float a = gg7[xx];
                #pragma unroll
                for (int kx = 0; kx < 4; ++kx)
                    a = fmaf(wc[ky*4 + kx], xrow[xx + kx], a);
                gg7[xx] = a;
            }
        }
    }
    #pragma unroll
    for (int xx = 0; xx < 7; ++xx) gg7[xx] = __fadd_rn(gg7[xx], cbias);

    // ---- LIF sim: 7-instruction asm step, VOP2 literals for 0.1/-0.2, vcc carry ----
    // dataflow identical to round-9 (bit-identical results, absmax 0.125 proven):
    //   imv = i - v; vdec = fma(0.1,imv,v); spike = vdec > 1;
    //   v = spike?0:vdec; m = 2m + spike; idec = fma(-0.2,i,i); i = idec + g
    float v[7], ii[7];
    unsigned int mlo[7], mhi[7];
    float fzero = 0.0f;
    #pragma unroll
    for (int xx = 0; xx < 7; ++xx) { v[xx] = 0.f; ii[xx] = 0.f; mlo[xx] = 0u; mhi[xx] = 0u; }

    #pragma unroll 4
    for (int t = 0; t < tlo; ++t) {
        #pragma unroll
        for (int xx = 0; xx < 7; ++xx) {
            float imv;
            asm("v_sub_f32 %[imv], %[i], %[v]\n\t"
                "v_fmac_f32 %[v], 0x3dcccccd, %[imv]\n\t"   // v += 0.1f*imv
                "v_cmp_lt_f32 vcc, 1.0, %[v]\n\t"
                "v_cndmask_b32 %[v], %[v], %[vz], vcc\n\t"
                "v_addc_co_u32 %[m], vcc, %[m], %[m], vcc\n\t"
                "v_fmac_f32 %[i], 0xbe4ccccd, %[i]\n\t"     // i += -0.2f*i
                "v_add_f32 %[i], %[i], %[g]"
                : [v]"+v"(v[xx]), [i]"+v"(ii[xx]), [m]"+v"(mlo[xx]), [imv]"=&v"(imv)
                : [vz]"v"(fzero), [g]"v"(gg7[xx])
                : "vcc");
        }
    }
    #pragma unroll 4
    for (int t = 0; t < thi; ++t) {
        #pragma unroll
        for (int xx = 0; xx < 7; ++xx) {
            float imv;
            asm("v_sub_f32 %[imv], %[i], %[v]\n\t"
                "v_fmac_f32 %[v], 0x3dcccccd, %[imv]\n\t"
                "v_cmp_lt_f32 vcc, 1.0, %[v]\n\t"
                "v_cndmask_b32 %[v], %[v], %[vz], vcc\n\t"
                "v_addc_co_u32 %[m], vcc, %[m], %[m], vcc\n\t"
                "v_fmac_f32 %[i], 0xbe4ccccd, %[i]\n\t"
                "v_add_f32 %[i], %[i], %[g]"
                : [v]"+v"(v[xx]), [i]"+v"(ii[xx]), [m]"+v"(mhi[xx]), [imv]"=&v"(imv)
                : [vz]"v"(fzero), [g]"v"(gg7[xx])
                : "vcc");
        }
    }

    // ---- neighbor-row masks via shfl (lane y+1, same c) ----
    unsigned int nlo[7], nhi[7];
    #pragma unroll
    for (int xx = 0; xx < 7; ++xx) {
        nlo[xx] = __shfl_down(mlo[xx], 1);
        nhi[xx] = __shfl_down(mhi[xx], 1);
    }

    // ---- pooled row y (if y<6): OR of 4 masks + LUT + FC partials ----
    float outacc[10];
    #pragma unroll
    for (int o = 0; o < 10; ++o) outacc[o] = 0.f;

    if (y < 6) {
        const int jbase = c * 36 + y * 6;
        #pragma unroll
        for (int px = 0; px < 6; ++px) {
            const unsigned int pl = mlo[px] | mlo[px+1] | nlo[px] | nlo[px+1];
            const unsigned int ph = mhi[px] | mhi[px+1] | nhi[px] | nhi[px+1];
            float a = s_tab[0][pl & 255] + s_tab[1][(pl >> 8) & 255]
                    + s_tab[2][(pl >> 16) & 255] + s_tab[3][pl >> 24]
                    + s_tab[4][ph & 255] + s_tab[5][(ph >> 8) & 255]
                    + s_tab[6][(ph >> 16) & 255] + s_tab[7][ph >> 24];
            const int j = jbase + px;
            #pragma unroll
            for (int o = 0; o < 10; ++o)
                outacc[o] = fmaf(s_fcw[o * 72 + j], a, outacc[o]);
        }
    }

    // ---- reduce over the 16-lane group, add bias response, store ----
    #pragma unroll
    for (int o = 0; o < 10; ++o) {
        float t = outacc[o];
        t += __shfl_xor(t, 1);
        t += __shfl_xor(t, 2);
        t += __shfl_xor(t, 4);
        t += __shfl_xor(t, 8);
        if (sub == 0) out[b * 10 + o] = fmaf(cbsum, s_fcb[o], t);
    }
}

extern "C" void kernel_launch(void* const* d_in, const int* in_sizes, int n_in,
                              void* d_out, int out_size, void* d_ws, size_t ws_size,
                              hipStream_t stream) {
    const float* x      = (const float*)d_in[0];
    const float* conv_w = (const float*)d_in[1];
    const float* conv_b = (const float*)d_in[2];
    const float* fc_w   = (const float*)d_in[3];
    const float* fc_b   = (const float*)d_in[4];
    const int*   nsteps = (const int*)d_in[5];
    float* outp = (float*)d_out;

    const int B = in_sizes[0] / 100;
    const int total = 16 * B;   // lane = c*8 + y per batch
    const int block = 256;
    const int grid = (total + block - 1) / block;
    snn_fused<<<grid, block, 0, stream>>>(x, conv_w, conv_b, fc_w, fc_b, nsteps, outp, B);
}

// Round 13
// 79.396 us; speedup vs baseline: 1.3736x; 1.0026x over previous
//
#include <hip/hip_runtime.h>

#define TMAX 64

// One LIF timestep, type-grouped for ILP, per-element SGPR carries (no vcc).
// Dataflow per element is EXACTLY round-11's (absmax 0.125 proven):
//   imv = i - v; v = fma(0.1,imv,v); spike = v > 1; v = spike?0:v;
//   m = 2m + spike; i = fma(-0.2,i,i); i = i + g     <-- +g kept as separate add
#define LIF_STEP_A(M) do {                                                    \
    float t0,t1,t2,t3; unsigned long long c0,c1,c2,c3;                        \
    asm("v_sub_f32 %[t0], %[i0], %[v0]\n\t"                                   \
        "v_sub_f32 %[t1], %[i1], %[v1]\n\t"                                   \
        "v_sub_f32 %[t2], %[i2], %[v2]\n\t"                                   \
        "v_sub_f32 %[t3], %[i3], %[v3]\n\t"                                   \
        "v_fmac_f32 %[v0], 0x3dcccccd, %[t0]\n\t"                             \
        "v_fmac_f32 %[v1], 0x3dcccccd, %[t1]\n\t"                             \
        "v_fmac_f32 %[v2], 0x3dcccccd, %[t2]\n\t"                             \
        "v_fmac_f32 %[v3], 0x3dcccccd, %[t3]\n\t"                             \
        "v_cmp_lt_f32 %[c0], 1.0, %[v0]\n\t"                                  \
        "v_cmp_lt_f32 %[c1], 1.0, %[v1]\n\t"                                  \
        "v_cmp_lt_f32 %[c2], 1.0, %[v2]\n\t"                                  \
        "v_cmp_lt_f32 %[c3], 1.0, %[v3]\n\t"                                  \
        "v_cndmask_b32 %[v0], %[v0], 0, %[c0]\n\t"                            \
        "v_cndmask_b32 %[v1], %[v1], 0, %[c1]\n\t"                            \
        "v_cndmask_b32 %[v2], %[v2], 0, %[c2]\n\t"                            \
        "v_cndmask_b32 %[v3], %[v3], 0, %[c3]\n\t"                            \
        "v_addc_co_u32 %[m0], %[c0], %[m0], %[m0], %[c0]\n\t"                 \
        "v_addc_co_u32 %[m1], %[c1], %[m1], %[m1], %[c1]\n\t"                 \
        "v_addc_co_u32 %[m2], %[c2], %[m2], %[m2], %[c2]\n\t"                 \
        "v_addc_co_u32 %[m3], %[c3], %[m3], %[m3], %[c3]\n\t"                 \
        "v_fmac_f32 %[i0], 0xbe4ccccd, %[i0]\n\t"                             \
        "v_fmac_f32 %[i1], 0xbe4ccccd, %[i1]\n\t"                             \
        "v_fmac_f32 %[i2], 0xbe4ccccd, %[i2]\n\t"                             \
        "v_fmac_f32 %[i3], 0xbe4ccccd, %[i3]\n\t"                             \
        "v_add_f32 %[i0], %[i0], %[g0]\n\t"                                   \
        "v_add_f32 %[i1], %[i1], %[g1]\n\t"                                   \
        "v_add_f32 %[i2], %[i2], %[g2]\n\t"                                   \
        "v_add_f32 %[i3], %[i3], %[g3]"                                       \
        : [v0]"+v"(v[0]), [v1]"+v"(v[1]), [v2]"+v"(v[2]), [v3]"+v"(v[3]),     \
          [i0]"+v"(ii[0]), [i1]"+v"(ii[1]), [i2]"+v"(ii[2]), [i3]"+v"(ii[3]), \
          [m0]"+v"(M[0]), [m1]"+v"(M[1]), [m2]"+v"(M[2]), [m3]"+v"(M[3]),     \
          [t0]"=&v"(t0), [t1]"=&v"(t1), [t2]"=&v"(t2), [t3]"=&v"(t3),         \
          [c0]"=&s"(c0), [c1]"=&s"(c1), [c2]"=&s"(c2), [c3]"=&s"(c3)          \
        : [g0]"v"(gg7[0]), [g1]"v"(gg7[1]), [g2]"v"(gg7[2]), [g3]"v"(gg7[3]));\
} while (0)

#define LIF_STEP_B(M) do {                                                    \
    float t4,t5,t6; unsigned long long c4,c5,c6;                              \
    asm("v_sub_f32 %[t4], %[i4], %[v4]\n\t"                                   \
        "v_sub_f32 %[t5], %[i5], %[v5]\n\t"                                   \
        "v_sub_f32 %[t6], %[i6], %[v6]\n\t"                                   \
        "v_fmac_f32 %[v4], 0x3dcccccd, %[t4]\n\t"                             \
        "v_fmac_f32 %[v5], 0x3dcccccd, %[t5]\n\t"                             \
        "v_fmac_f32 %[v6], 0x3dcccccd, %[t6]\n\t"                             \
        "v_cmp_lt_f32 %[c4], 1.0, %[v4]\n\t"                                  \
        "v_cmp_lt_f32 %[c5], 1.0, %[v5]\n\t"                                  \
        "v_cmp_lt_f32 %[c6], 1.0, %[v6]\n\t"                                  \
        "v_cndmask_b32 %[v4], %[v4], 0, %[c4]\n\t"                            \
        "v_cndmask_b32 %[v5], %[v5], 0, %[c5]\n\t"                            \
        "v_cndmask_b32 %[v6], %[v6], 0, %[c6]\n\t"                            \
        "v_addc_co_u32 %[m4], %[c4], %[m4], %[m4], %[c4]\n\t"                 \
        "v_addc_co_u32 %[m5], %[c5], %[m5], %[m5], %[c5]\n\t"                 \
        "v_addc_co_u32 %[m6], %[c6], %[m6], %[m6], %[c6]\n\t"                 \
        "v_fmac_f32 %[i4], 0xbe4ccccd, %[i4]\n\t"                             \
        "v_fmac_f32 %[i5], 0xbe4ccccd, %[i5]\n\t"                             \
        "v_fmac_f32 %[i6], 0xbe4ccccd, %[i6]\n\t"                             \
        "v_add_f32 %[i4], %[i4], %[g4]\n\t"                                   \
        "v_add_f32 %[i5], %[i5], %[g5]\n\t"                                   \
        "v_add_f32 %[i6], %[i6], %[g6]"                                       \
        : [v4]"+v"(v[4]), [v5]"+v"(v[5]), [v6]"+v"(v[6]),                     \
          [i4]"+v"(ii[4]), [i5]"+v"(ii[5]), [i6]"+v"(ii[6]),                  \
          [m4]"+v"(M[4]), [m5]"+v"(M[5]), [m6]"+v"(M[6]),                     \
          [t4]"=&v"(t4), [t5]"=&v"(t5), [t6]"=&v"(t6),                        \
          [c4]"=&s"(c4), [c5]"=&s"(c5), [c6]"=&s"(c6)                         \
        : [g4]"v"(gg7[4]), [g5]"v"(gg7[5]), [g6]"v"(gg7[6]));                 \
} while (0)

__global__ __launch_bounds__(256) void snn_fused(
    const float* __restrict__ x,       // [B,1,10,10]
    const float* __restrict__ conv_w,  // [2,1,4,4]
    const float* __restrict__ conv_b,  // [2]
    const float* __restrict__ fc_w,    // [10,72]
    const float* __restrict__ fc_b,    // [10]
    const int*   __restrict__ nsteps,  // scalar
    float*       __restrict__ out,     // [B,10]
    int B)
{
    __shared__ double d_F[TMAX];       // F(m) = 0.9^m - 0.8^m  (double)
    __shared__ float  s_r[TMAX];       // r_s = G(T-1-s)  (time-indexed)
    __shared__ float  s_rb[TMAX];      // bit-position -> r  (addc bit order)
    __shared__ float  s_tab[8][256];   // byte tables over s_rb
    __shared__ float  s_fcw[720];
    __shared__ float  s_fcb[16];
    __shared__ float  s_cb;            // C_b = sum_{m<T} F(m)

    const int tid = threadIdx.x;
    int T = nsteps[0];
    if (T > TMAX) T = TMAX;
    if (T < 0) T = 0;
    const int tlo = T < 32 ? T : 32;
    const int thi = T > 32 ? (T - 32) : 0;

    // --- setup: F(m) in double ---
    if (tid < TMAX) {
        double p9 = 1.0, p8 = 1.0;
        for (int k = 0; k < tid; ++k) { p9 *= 0.9; p8 *= 0.8; }
        d_F[tid] = p9 - p8;
    }
    for (int idx = tid; idx < 720; idx += 256) s_fcw[idx] = fc_w[idx];
    if (tid < 10) s_fcb[tid] = fc_b[tid];
    __syncthreads();

    // --- r_s = G(T-1-s), double accumulate ---
    if (tid < TMAX) {
        double r = 0.0;
        if (tid < T) {
            const int n = T - 1 - tid;
            for (int u = 0; u <= n; ++u) r += d_F[n - u] * d_F[u];
        }
        s_r[tid] = (float)r;
    }
    if (tid == 0) {
        double cb = 0.0;
        for (int m = 0; m < T; ++m) cb += d_F[m];
        s_cb = (float)cb;
    }
    __syncthreads();

    // --- bit-position -> r map (m = 2m + sp ordering) ---
    if (tid < 32) {
        s_rb[tid] = (tid < tlo) ? s_r[tlo - 1 - tid] : 0.f;
    } else if (tid < 64) {
        const int p = tid - 32;
        s_rb[tid] = (p < thi) ? s_r[tlo + thi - 1 - p] : 0.f;
    }
    __syncthreads();

    // --- byte lookup tables ---
    {
        const int v8 = tid; // 0..255
        #pragma unroll
        for (int k = 0; k < 8; ++k) {
            float ssum = 0.f;
            #pragma unroll
            for (int bb = 0; bb < 8; ++bb)
                if ((v8 >> bb) & 1) ssum += s_rb[k * 8 + bb];
            s_tab[k][v8] = ssum;
        }
    }
    __syncthreads();

    const float cbsum = s_cb;

    // lane mapping: 16 lanes per batch: sub = c*8 + y; y==7 lanes pad (clamp to row 6)
    const int gt  = blockIdx.x * 256 + tid;
    const int sub = gt & 15;
    const int b   = gt >> 4;
    const int c   = sub >> 3;
    const int y   = sub & 7;
    const int ysim = (y < 6) ? y : 6;
    if (b >= B) return;

    const float* xb = x + b * 100;
    const float cbias = conv_b[c];

    // ---- conv for row ysim: fma-contracted (ky asc, kx asc) order, then +bias ----
    float gg7[7];
    #pragma unroll
    for (int xx = 0; xx < 7; ++xx) gg7[xx] = 0.f;
    {
        float wc[16];
        const float4* wq = reinterpret_cast<const float4*>(conv_w + c * 16);
        #pragma unroll
        for (int k = 0; k < 4; ++k) {
            float4 t = wq[k];
            wc[4*k+0] = t.x; wc[4*k+1] = t.y; wc[4*k+2] = t.z; wc[4*k+3] = t.w;
        }
        #pragma unroll
        for (int ky = 0; ky < 4; ++ky) {
            float xrow[10];
            const float2* q = reinterpret_cast<const float2*>(xb + (ysim + ky) * 10);
            #pragma unroll
            for (int k = 0; k < 5; ++k) { float2 t = q[k]; xrow[2*k] = t.x; xrow[2*k+1] = t.y; }
            #pragma unroll
            for (int xx = 0; xx < 7; ++xx) {
                float a = gg7[xx];
                #pragma unroll
                for (int kx = 0; kx < 4; ++kx)
                    a = fmaf(wc[ky*4 + kx], xrow[xx + kx], a);
                gg7[xx] = a;
            }
        }
    }
    #pragma unroll
    for (int xx = 0; xx < 7; ++xx) gg7[xx] = __fadd_rn(gg7[xx], cbias);

    // ---- LIF sim: 7-instr/elem grouped asm, SGPR carries, no vcc ----
    float v[7], ii[7];
    unsigned int mlo[7], mhi[7];
    #pragma unroll
    for (int xx = 0; xx < 7; ++xx) { v[xx] = 0.f; ii[xx] = 0.f; mlo[xx] = 0u; mhi[xx] = 0u; }

    #pragma unroll 4
    for (int t = 0; t < tlo; ++t) {
        LIF_STEP_A(mlo);
        LIF_STEP_B(mlo);
    }
    #pragma unroll 4
    for (int t = 0; t < thi; ++t) {
        LIF_STEP_A(mhi);
        LIF_STEP_B(mhi);
    }

    // ---- neighbor-row masks via shfl (lane y+1, same c) ----
    unsigned int nlo[7], nhi[7];
    #pragma unroll
    for (int xx = 0; xx < 7; ++xx) {
        nlo[xx] = __shfl_down(mlo[xx], 1);
        nhi[xx] = __shfl_down(mhi[xx], 1);
    }

    // ---- pooled row y (if y<6): OR of 4 masks + LUT + FC partials ----
    float outacc[10];
    #pragma unroll
    for (int o = 0; o < 10; ++o) outacc[o] = 0.f;

    if (y < 6) {
        const int jbase = c * 36 + y * 6;
        #pragma unroll
        for (int px = 0; px < 6; ++px) {
            const unsigned int pl = mlo[px] | mlo[px+1] | nlo[px] | nlo[px+1];
            const unsigned int ph = mhi[px] | mhi[px+1] | nhi[px] | nhi[px+1];
            float a = s_tab[0][pl & 255] + s_tab[1][(pl >> 8) & 255]
                    + s_tab[2][(pl >> 16) & 255] + s_tab[3][pl >> 24]
                    + s_tab[4][ph & 255] + s_tab[5][(ph >> 8) & 255]
                    + s_tab[6][(ph >> 16) & 255] + s_tab[7][ph >> 24];
            const int j = jbase + px;
            #pragma unroll
            for (int o = 0; o < 10; ++o)
                outacc[o] = fmaf(s_fcw[o * 72 + j], a, outacc[o]);
        }
    }

    // ---- reduce over the 16-lane group, add bias response, store ----
    #pragma unroll
    for (int o = 0; o < 10; ++o) {
        float t = outacc[o];
        t += __shfl_xor(t, 1);
        t += __shfl_xor(t, 2);
        t += __shfl_xor(t, 4);
        t += __shfl_xor(t, 8);
        if (sub == 0) out[b * 10 + o] = fmaf(cbsum, s_fcb[o], t);
    }
}

extern "C" void kernel_launch(void* const* d_in, const int* in_sizes, int n_in,
                              void* d_out, int out_size, void* d_ws, size_t ws_size,
                              hipStream_t stream) {
    const float* x      = (const float*)d_in[0];
    const float* conv_w = (const float*)d_in[1];
    const float* conv_b = (const float*)d_in[2];
    const float* fc_w   = (const float*)d_in[3];
    const float* fc_b   = (const float*)d_in[4];
    const int*   nsteps = (const int*)d_in[5];
    float* outp = (float*)d_out;

    const int B = in_sizes[0] / 100;
    const int total = 16 * B;   // lane = c*8 + y per batch
    const int block = 256;
    const int grid = (total + block - 1) / block;
    snn_fused<<<grid, block, 0, stream>>>(x, conv_w, conv_b, fc_w, fc_b, nsteps, outp, B);
}